// Round 5
// baseline (328.732 us; speedup 1.0000x reference)
//
#include <hip/hip_runtime.h>

typedef __bf16 bf16;
typedef __attribute__((ext_vector_type(8))) __bf16 bf16x8;
typedef __attribute__((ext_vector_type(4))) __bf16 bf16x4;
typedef __attribute__((ext_vector_type(4))) float f32x4;

constexpr int T_SEQ = 2048;
constexpr int DIM   = 2048;
constexpr int NH    = 32;
constexpr int NKV   = 8;
constexpr int HD    = 64;
constexpr int QKV_N = DIM + 2 * NKV * HD;   // 3072
constexpr int MROWS = 2 * T_SEQ;            // 4096 (B*T)

// ---------------- cast f32 -> bf16 ----------------
__global__ void cast_kernel(const float* __restrict__ in, bf16* __restrict__ out, int n) {
  int stride = gridDim.x * blockDim.x * 4;
  for (int i = (blockIdx.x * blockDim.x + threadIdx.x) * 4; i < n; i += stride) {
    float4 v = *(const float4*)(in + i);
    bf16x4 o = { (bf16)v.x, (bf16)v.y, (bf16)v.z, (bf16)v.w };
    *(bf16x4*)(out + i) = o;
  }
}

// ---------------- GEMM: C[m][n] = sum_k A[m][k] * W[n][k] ----------------
template <typename OutT>
__global__ __launch_bounds__(256) void gemm_bt(const bf16* __restrict__ A,
                                               const bf16* __restrict__ W,
                                               OutT* __restrict__ C,
                                               int M, int N, int K) {
  constexpr int BM = 128, BN = 128, BK = 64;
  __shared__ __attribute__((aligned(16))) bf16 Ab[BM * BK];
  __shared__ __attribute__((aligned(16))) bf16 Bb[BN * BK];
  const int tid  = threadIdx.x;
  const int lane = tid & 63, wave = tid >> 6;
  const int bm = blockIdx.x * BM, bn = blockIdx.y * BN;
  const int wm = (wave >> 1) * 64, wn = (wave & 1) * 64;
  const int l15 = lane & 15, l4 = lane >> 4;

  f32x4 acc[4][4] = {};

  for (int k0 = 0; k0 < K; k0 += BK) {
    for (int i = 0; i < 4; ++i) {
      int chunk = i * 256 + tid;
      int r = chunk >> 3, c = (chunk & 7) << 3;
      __builtin_amdgcn_global_load_lds(
          (const __attribute__((address_space(1))) unsigned int*)(A + (size_t)(bm + r) * K + k0 + c),
          (__attribute__((address_space(3))) unsigned int*)(Ab + chunk * 8), 16, 0, 0);
      __builtin_amdgcn_global_load_lds(
          (const __attribute__((address_space(1))) unsigned int*)(W + (size_t)(bn + r) * K + k0 + c),
          (__attribute__((address_space(3))) unsigned int*)(Bb + chunk * 8), 16, 0, 0);
    }
    __syncthreads();
    #pragma unroll
    for (int kk = 0; kk < 2; ++kk) {
      const int co = kk * 32 + l4 * 8;
      bf16x8 af[4], bfr[4];
      #pragma unroll
      for (int mi = 0; mi < 4; ++mi)
        af[mi] = *(const bf16x8*)(Ab + (wm + mi * 16 + l15) * BK + co);
      #pragma unroll
      for (int ni = 0; ni < 4; ++ni)
        bfr[ni] = *(const bf16x8*)(Bb + (wn + ni * 16 + l15) * BK + co);
      #pragma unroll
      for (int mi = 0; mi < 4; ++mi)
        #pragma unroll
        for (int ni = 0; ni < 4; ++ni)
          acc[mi][ni] = __builtin_amdgcn_mfma_f32_16x16x32_bf16(af[mi], bfr[ni], acc[mi][ni], 0, 0, 0);
    }
    __syncthreads();
  }

  #pragma unroll
  for (int mi = 0; mi < 4; ++mi)
    #pragma unroll
    for (int ni = 0; ni < 4; ++ni) {
      size_t row = (size_t)bm + wm + mi * 16 + l4 * 4;
      int col = bn + wn + ni * 16 + l15;
      #pragma unroll
      for (int r = 0; r < 4; ++r)
        C[(row + r) * N + col] = (OutT)acc[mi][ni][r];
    }
}

// ---------------- RoPE, vectorized: 16 bf16 (8 pairs) per thread ----------------
__global__ void rope_kernel(bf16* __restrict__ qkv, const float* __restrict__ cs,
                            const float* __restrict__ sn) {
  int idx = blockIdx.x * blockDim.x + threadIdx.x;   // MROWS*160 total
  int m = idx / 160;
  int ch = idx - m * 160;
  int t = m & (T_SEQ - 1);
  int col, c;
  if (ch < 128) { int hh = ch >> 2; c = ch & 3; col = hh * 64 + c * 16; }
  else          { int ch2 = ch - 128; int hh = ch2 >> 2; c = ch2 & 3; col = DIM + hh * 64 + c * 16; }
  bf16* ptr = qkv + (size_t)m * QKV_N + col;
  bf16x8 v0 = *(bf16x8*)ptr, v1 = *(bf16x8*)(ptr + 8);
  const float* cp = cs + t * 32 + c * 8;
  const float* sp = sn + t * 32 + c * 8;
  float4 c0 = *(const float4*)cp, c1 = *(const float4*)(cp + 4);
  float4 s0 = *(const float4*)sp, s1 = *(const float4*)(sp + 4);
  float cc[8] = {c0.x, c0.y, c0.z, c0.w, c1.x, c1.y, c1.z, c1.w};
  float ss[8] = {s0.x, s0.y, s0.z, s0.w, s1.x, s1.y, s1.z, s1.w};
  bf16x8 o0, o1;
  #pragma unroll
  for (int j = 0; j < 4; ++j) {
    float a = (float)v0[2 * j], b = (float)v0[2 * j + 1];
    o0[2 * j]     = (bf16)(a * cc[j] - b * ss[j]);
    o0[2 * j + 1] = (bf16)(a * ss[j] + b * cc[j]);
  }
  #pragma unroll
  for (int j = 0; j < 4; ++j) {
    float a = (float)v1[2 * j], b = (float)v1[2 * j + 1];
    o1[2 * j]     = (bf16)(a * cc[4 + j] - b * ss[4 + j]);
    o1[2 * j + 1] = (bf16)(a * ss[4 + j] + b * cc[4 + j]);
  }
  *(bf16x8*)ptr = o0;
  *(bf16x8*)(ptr + 8) = o1;
}

// ---------------- Flash attention, causal GQA ----------------
// grid (8, NH, B); 8 waves (512 thr). Waves 0-3 own 128-row strip qpair,
// waves 4-7 own strip 15-qpair (32 q-rows per wave, 2 fragments of 16).
// Swapped QK^T (mfma(K,Q)): lane holds one q-row's 16 k-values -> in-register
// softmax reduce + 2 shfl_xor. Packed b64 P-writes. Double-buffered K/V,
// one barrier per kv-tile. 34 compute-tiles per block (uniform).
__global__ __launch_bounds__(512, 4) void attn_kernel(const bf16* __restrict__ qkv,
                                                      bf16* __restrict__ y) {
  const int qpair = blockIdx.x, h = blockIdx.y, b = blockIdx.z;
  const int g = h >> 2;  // kv head
  const int tid = threadIdx.x, lane = tid & 63, wave = tid >> 6;
  const int l15 = lane & 15, l4 = lane >> 4;
  const int strip = (wave < 4) ? qpair : (15 - qpair);
  const int w4 = wave & 3;
  const int qbase = strip * 128 + w4 * 32;

  __shared__ __attribute__((aligned(16))) bf16 Kb[2][64 * 64];   // [kv][d], swizzled
  __shared__ __attribute__((aligned(16))) bf16 VTs[2][64 * 64];  // [d][kv], swizzled
  __shared__ __attribute__((aligned(16))) bf16 Pb[8][32 * 64];   // per-wave [q][kv], swizzled

  constexpr float SCALE2 = 0.125f * 1.44269504088896f;  // scale * log2(e)

  // Q fragments (B-operand of swapped QK^T): frag f rows qbase+f*16+l15
  bf16x8 qf[2][2];
  #pragma unroll
  for (int f = 0; f < 2; ++f) {
    const bf16* qp = qkv + ((size_t)b * T_SEQ + qbase + f * 16 + l15) * QKV_N + h * HD + l4 * 8;
    qf[f][0] = *(const bf16x8*)(qp);
    qf[f][1] = *(const bf16x8*)(qp + 32);
  }

  f32x4 oacc[2][4] = {};
  float m_run[2] = {-INFINITY, -INFINITY}, l_run[2] = {0.f, 0.f};

  const int last_kt = (qbase + 31) >> 6;     // last tile this wave computes
  const int nt_loop = 32 - 2 * qpair;        // tiles staged (hi strip needs)
  const size_t kvbase = (size_t)b * T_SEQ;

  const int sr = tid >> 3, sc8 = (tid & 7) << 3;
  const int scsrc = sc8 ^ ((sr & 7) << 3);   // pre-swizzled K source col

  // ---- prologue: stage tile 0 into buffer 0 ----
  {
    __builtin_amdgcn_global_load_lds(
        (const __attribute__((address_space(1))) unsigned int*)
            (qkv + (kvbase + sr) * QKV_N + DIM + g * HD + scsrc),
        (__attribute__((address_space(3))) unsigned int*)(&Kb[0][0] + tid * 8), 16, 0, 0);
    const bf16* vp = qkv + (kvbase + wave * 8) * QKV_N + DIM + NKV * HD + g * HD + lane;
    bf16x8 vr;
    #pragma unroll
    for (int j = 0; j < 8; ++j) vr[j] = vp[(size_t)j * QKV_N];
    *(bf16x8*)((char*)&VTs[0][0] + ((lane * 128 + wave * 16) ^ ((lane & 7) << 4))) = vr;
    asm volatile("s_waitcnt vmcnt(0)" ::: "memory");
    __syncthreads();
  }

  int cur = 0;
  for (int kt = 0; kt < nt_loop; ++kt) {
    const bool has_next = (kt + 1) < nt_loop;
    bf16x8 vr;
    if (has_next) {
      __builtin_amdgcn_global_load_lds(
          (const __attribute__((address_space(1))) unsigned int*)
              (qkv + (kvbase + (kt + 1) * 64 + sr) * QKV_N + DIM + g * HD + scsrc),
          (__attribute__((address_space(3))) unsigned int*)(&Kb[cur ^ 1][0] + tid * 8), 16, 0, 0);
      const bf16* vp = qkv + (kvbase + (kt + 1) * 64 + wave * 8) * QKV_N
                           + DIM + NKV * HD + g * HD + lane;
      #pragma unroll
      for (int j = 0; j < 8; ++j) vr[j] = vp[(size_t)j * QKV_N];
    }

    if (kt <= last_kt) {
      const bf16* kb = &Kb[cur][0];
      const bf16* vt = &VTs[cur][0];

      // ---- S^T = K Q^T : z[f][nt], lane = (q=f*16+l15, k=nt*16+l4*4+r) ----
      f32x4 z[2][4];
      #pragma unroll
      for (int f = 0; f < 2; ++f)
        #pragma unroll
        for (int nt = 0; nt < 4; ++nt) z[f][nt] = (f32x4){0.f, 0.f, 0.f, 0.f};
      #pragma unroll
      for (int nt = 0; nt < 4; ++nt)
        #pragma unroll
        for (int kk = 0; kk < 2; ++kk) {
          bf16x8 kf = *(const bf16x8*)((const char*)kb +
              (((nt * 16 + l15) * 128 + (kk * 32 + l4 * 8) * 2) ^ ((l15 & 7) << 4)));
          z[0][nt] = __builtin_amdgcn_mfma_f32_16x16x32_bf16(kf, qf[0][kk], z[0][nt], 0, 0, 0);
          z[1][nt] = __builtin_amdgcn_mfma_f32_16x16x32_bf16(kf, qf[1][kk], z[1][nt], 0, 0, 0);
        }

      const bool domask = (kt == last_kt);
      bf16* pbw = &Pb[wave][0];

      #pragma unroll
      for (int f = 0; f < 2; ++f) {
        const int qg = qbase + f * 16 + l15;
        float s[4][4];
        #pragma unroll
        for (int nt = 0; nt < 4; ++nt)
          #pragma unroll
          for (int r = 0; r < 4; ++r) {
            float v = z[f][nt][r] * SCALE2;
            if (domask && (kt * 64 + nt * 16 + l4 * 4 + r > qg)) v = -INFINITY;
            s[nt][r] = v;
          }

        // row max: 16 in-register + 2 cross-group shfl
        float vm = s[0][0];
        #pragma unroll
        for (int nt = 0; nt < 4; ++nt)
          #pragma unroll
          for (int r = 0; r < 4; ++r) vm = fmaxf(vm, s[nt][r]);
        vm = fmaxf(vm, __shfl_xor(vm, 16));
        vm = fmaxf(vm, __shfl_xor(vm, 32));
        float mnew = fmaxf(m_run[f], vm);
        float alpha = __builtin_amdgcn_exp2f(m_run[f] - mnew);
        m_run[f] = mnew;

        // P = exp2(s - m), in-register sum + 2 shfl
        float p[4][4];
        float ps = 0.f;
        #pragma unroll
        for (int nt = 0; nt < 4; ++nt)
          #pragma unroll
          for (int r = 0; r < 4; ++r) {
            float pv = __builtin_amdgcn_exp2f(s[nt][r] - mnew);
            p[nt][r] = pv;
            ps += pv;
          }
        ps += __shfl_xor(ps, 16);
        ps += __shfl_xor(ps, 32);
        l_run[f] = l_run[f] * alpha + ps;

        // broadcast alpha to O-row holders (q=l4*4+r) and rescale oacc
        #pragma unroll
        for (int r = 0; r < 4; ++r) {
          float ab = __shfl(alpha, (lane & 48) | (l4 * 4 + r));
          #pragma unroll
          for (int dt = 0; dt < 4; ++dt) oacc[f][dt][r] *= ab;
        }

        // packed P write: row = f*16+l15, 4 consecutive k per nt -> b64
        const int row = f * 16 + l15;
        #pragma unroll
        for (int nt = 0; nt < 4; ++nt) {
          bf16x4 pk = { (bf16)p[nt][0], (bf16)p[nt][1], (bf16)p[nt][2], (bf16)p[nt][3] };
          *(bf16x4*)((char*)pbw + ((row * 128 + nt * 32 + l4 * 8) ^ ((row & 7) << 4))) = pk;
        }
      }

      // ---- O += P @ V ----
      #pragma unroll
      for (int kk = 0; kk < 2; ++kk) {
        bf16x8 pf0 = *(const bf16x8*)((const char*)pbw +
            ((l15 * 128 + kk * 64 + l4 * 16) ^ ((l15 & 7) << 4)));
        bf16x8 pf1 = *(const bf16x8*)((const char*)pbw +
            (((16 + l15) * 128 + kk * 64 + l4 * 16) ^ ((l15 & 7) << 4)));
        #pragma unroll
        for (int dt = 0; dt < 4; ++dt) {
          bf16x8 vf = *(const bf16x8*)((const char*)vt +
              (((dt * 16 + l15) * 128 + (kk * 32 + l4 * 8) * 2) ^ ((l15 & 7) << 4)));
          oacc[0][dt] = __builtin_amdgcn_mfma_f32_16x16x32_bf16(pf0, vf, oacc[0][dt], 0, 0, 0);
          oacc[1][dt] = __builtin_amdgcn_mfma_f32_16x16x32_bf16(pf1, vf, oacc[1][dt], 0, 0, 0);
        }
      }
    }

    if (has_next) {
      *(bf16x8*)((char*)&VTs[cur ^ 1][0] + ((lane * 128 + wave * 16) ^ ((lane & 7) << 4))) = vr;
      asm volatile("s_waitcnt vmcnt(0)" ::: "memory");
      __syncthreads();
      cur ^= 1;
    }
  }

  // ---- epilogue: O rows q=qbase+f*16+l4*4+r, cols d=dt*16+l15 ----
  #pragma unroll
  for (int f = 0; f < 2; ++f)
    #pragma unroll
    for (int r = 0; r < 4; ++r) {
      float lb = __shfl(l_run[f], (lane & 48) | (l4 * 4 + r));
      float linv = __builtin_amdgcn_rcpf(lb);
      #pragma unroll
      for (int dt = 0; dt < 4; ++dt) {
        y[((size_t)b * T_SEQ + qbase + f * 16 + l4 * 4 + r) * DIM + h * HD + dt * 16 + l15] =
            (bf16)(oacc[f][dt][r] * linv);
      }
    }
}

// ---------------- launch ----------------
extern "C" void kernel_launch(void* const* d_in, const int* in_sizes, int n_in,
                              void* d_out, int out_size, void* d_ws, size_t ws_size,
                              hipStream_t stream) {
  const float* x    = (const float*)d_in[0];
  const float* cosb = (const float*)d_in[1];
  const float* sinb = (const float*)d_in[2];
  const float* wq   = (const float*)d_in[3];
  const float* wk   = (const float*)d_in[4];
  const float* wv   = (const float*)d_in[5];
  const float* wo   = (const float*)d_in[6];
  float* out = (float*)d_out;

  bf16* xb   = (bf16*)d_ws;                           // 4096*2048
  bf16* wqkv = xb + (size_t)MROWS * DIM;              // 3072*2048
  bf16* wob  = wqkv + (size_t)QKV_N * DIM;            // 2048*2048
  bf16* qkv  = wob + (size_t)DIM * DIM;               // 4096*3072
  bf16* y    = qkv + (size_t)MROWS * QKV_N;           // 4096*2048

  cast_kernel<<<2048, 256, 0, stream>>>(x, xb, MROWS * DIM);
  cast_kernel<<<2048, 256, 0, stream>>>(wq, wqkv, DIM * DIM);
  cast_kernel<<<512, 256, 0, stream>>>(wk, wqkv + (size_t)DIM * DIM, NKV * HD * DIM);
  cast_kernel<<<512, 256, 0, stream>>>(wv, wqkv + (size_t)(DIM + NKV * HD) * DIM, NKV * HD * DIM);
  cast_kernel<<<2048, 256, 0, stream>>>(wo, wob, DIM * DIM);

  // QKV projection: M=4096, N=3072, K=2048
  gemm_bt<bf16><<<dim3(MROWS / 128, QKV_N / 128), 256, 0, stream>>>(xb, wqkv, qkv, MROWS, QKV_N, DIM);

  // RoPE on q,k
  rope_kernel<<<(MROWS * 160) / 256, 256, 0, stream>>>(qkv, cosb, sinb);

  // attention: balanced 128-row strip pairs, 32 q-rows/wave
  attn_kernel<<<dim3(8, NH, 2), 512, 0, stream>>>(qkv, y);

  // output projection: M=4096, N=2048, K=2048, f32 out
  gemm_bt<float><<<dim3(MROWS / 128, DIM / 128), 256, 0, stream>>>(y, wob, out, MROWS, DIM, DIM);
}